// Round 1
// baseline (176.785 us; speedup 1.0000x reference)
//
#include <hip/hip_runtime.h>

#define NN 40000
#define NE 640000
#define CAP 64
#define BN_EPS 1e-5f

// ---------------- zero cursor + BN accumulators ----------------
__global__ __launch_bounds__(256) void k_zero(int* __restrict__ cursor, float* __restrict__ bn) {
    int i = blockIdx.x * 256 + threadIdx.x;
    if (i < NN) cursor[i] = 0;
    int j = i - NN;
    if (j >= 0 && j < 256) bn[j] = 0.f;
}

// ---------------- bucket edges by dst (1 int atomic per edge) ----------------
__global__ __launch_bounds__(256) void k_bucket(const int* __restrict__ ei, int* __restrict__ cursor,
                                                int* __restrict__ srclist) {
    int e = blockIdx.x * 256 + threadIdx.x;
    if (e >= NE) return;
    int s = ei[e];
    int d = ei[NE + e];
    int pos = atomicAdd(&cursor[d], 1);
    if (pos < CAP) srclist[d * CAP + pos] = s;
}

// ---------------- wave-per-node gather-sum: hbuf = (1+eps)*x + sum_neighbors x ----------------
__global__ __launch_bounds__(256) void k_gather(const float* __restrict__ x, const int* __restrict__ cursor,
                                                const int* __restrict__ srclist, const float* __restrict__ epsp,
                                                float* __restrict__ hbuf) {
    int wid = blockIdx.x * 4 + (threadIdx.x >> 6);   // one wave per dst node; grid*4 == NN exactly
    int lane = threadIdx.x & 63;
    const float2* xv = (const float2*)x;
    int deg = cursor[wid];
    deg = deg > CAP ? CAP : deg;
    float2 self = xv[wid * 64 + lane];
    float e1 = 1.f + epsp[0];
    float a0 = self.x * e1, a1 = self.y * e1;
    const int* lst = srclist + wid * CAP;
    for (int i = 0; i < deg; ++i) {
        int s = lst[i];                 // wave-uniform
        float2 v = xv[s * 64 + lane];   // coalesced 512B row read
        a0 += v.x; a1 += v.y;
    }
    ((float2*)hbuf)[wid * 64 + lane] = make_float2(a0, a1);
}

// ---------------- fp32 vector GEMM: out[M,128] = A[M,128] @ W[128,128]^T + bias ----------------
// STATS: accumulate per-channel sum/sumsq of output (for BN).  BN: apply y=relu(a*scale+shift) to A on load.
template<bool STATS, bool BN>
__global__ __launch_bounds__(256) void k_gemm(const float* __restrict__ A, const float* __restrict__ W,
                                              const float* __restrict__ bias, float* __restrict__ out,
                                              const float* __restrict__ scale, const float* __restrict__ shift,
                                              float* __restrict__ bnsum, float* __restrict__ bnsumsq) {
    __shared__ float sA[64 * 65];    // 64 rows x 64 k (stride 65: <=2-way bank aliasing, free)
    __shared__ float sW[128 * 65];   // 128 cols x 64 k
    const int tid = threadIdx.x;
    const int tx = tid & 15;
    const int ty = tid >> 4;
    const int rb = blockIdx.x * 64;  // 40000 % 64 == 0: no row guards needed

    float acc[4][8];
#pragma unroll
    for (int i = 0; i < 4; ++i)
#pragma unroll
        for (int j = 0; j < 8; ++j) acc[i][j] = 0.f;

    for (int kb = 0; kb < 128; kb += 64) {
        __syncthreads();
        // stage A-tile (64x64), optionally with BN+ReLU fused
#pragma unroll
        for (int it = 0; it < 4; ++it) {
            int idx = it * 256 + tid;
            int r = idx >> 4;
            int kq = idx & 15;
            float4 v = *(const float4*)&A[(size_t)(rb + r) * 128 + kb + kq * 4];
            if (BN) {
                float4 sc = *(const float4*)&scale[kb + kq * 4];
                float4 sh = *(const float4*)&shift[kb + kq * 4];
                v.x = fmaxf(0.f, fmaf(v.x, sc.x, sh.x));
                v.y = fmaxf(0.f, fmaf(v.y, sc.y, sh.y));
                v.z = fmaxf(0.f, fmaf(v.z, sc.z, sh.z));
                v.w = fmaxf(0.f, fmaf(v.w, sc.w, sh.w));
            }
            float* d = &sA[r * 65 + kq * 4];
            d[0] = v.x; d[1] = v.y; d[2] = v.z; d[3] = v.w;
        }
        // stage W-tile (128x64), row-major as given (out[c] = sum_k A[k]*W[c][k])
#pragma unroll
        for (int it = 0; it < 8; ++it) {
            int idx = it * 256 + tid;
            int c = idx >> 4;
            int kq = idx & 15;
            float4 v = *(const float4*)&W[c * 128 + kb + kq * 4];
            float* d = &sW[c * 65 + kq * 4];
            d[0] = v.x; d[1] = v.y; d[2] = v.z; d[3] = v.w;
        }
        __syncthreads();
#pragma unroll 4
        for (int k = 0; k < 64; ++k) {
            float a[4], w[8];
#pragma unroll
            for (int i = 0; i < 4; ++i) a[i] = sA[(ty * 4 + i) * 65 + k];
#pragma unroll
            for (int j = 0; j < 4; ++j) {
                w[j]     = sW[(tx * 4 + j) * 65 + k];
                w[j + 4] = sW[(tx * 4 + 64 + j) * 65 + k];
            }
#pragma unroll
            for (int i = 0; i < 4; ++i)
#pragma unroll
                for (int j = 0; j < 8; ++j)
                    acc[i][j] = fmaf(a[i], w[j], acc[i][j]);
        }
    }

    const int c0 = tx * 4, c1 = tx * 4 + 64;
    float4 b0 = *(const float4*)&bias[c0];
    float4 b1v = *(const float4*)&bias[c1];
    float cs[8], cq[8];
#pragma unroll
    for (int j = 0; j < 8; ++j) { cs[j] = 0.f; cq[j] = 0.f; }
#pragma unroll
    for (int i = 0; i < 4; ++i) {
        int row = rb + ty * 4 + i;
        float4 v0, v1;
        v0.x = acc[i][0] + b0.x;  v0.y = acc[i][1] + b0.y;  v0.z = acc[i][2] + b0.z;  v0.w = acc[i][3] + b0.w;
        v1.x = acc[i][4] + b1v.x; v1.y = acc[i][5] + b1v.y; v1.z = acc[i][6] + b1v.z; v1.w = acc[i][7] + b1v.w;
        *(float4*)&out[(size_t)row * 128 + c0] = v0;
        *(float4*)&out[(size_t)row * 128 + c1] = v1;
        if (STATS) {
            cs[0] += v0.x; cq[0] += v0.x * v0.x;
            cs[1] += v0.y; cq[1] += v0.y * v0.y;
            cs[2] += v0.z; cq[2] += v0.z * v0.z;
            cs[3] += v0.w; cq[3] += v0.w * v0.w;
            cs[4] += v1.x; cq[4] += v1.x * v1.x;
            cs[5] += v1.y; cq[5] += v1.y * v1.y;
            cs[6] += v1.z; cq[6] += v1.z * v1.z;
            cs[7] += v1.w; cq[7] += v1.w * v1.w;
        }
    }
    if (STATS) {
        __syncthreads();           // everyone done reading sA/sW
        float* rs = sA;            // reuse LDS: 256 threads x 8 floats
        float* rq = sW;
#pragma unroll
        for (int j = 0; j < 8; ++j) { rs[tid * 8 + j] = cs[j]; rq[tid * 8 + j] = cq[j]; }
        __syncthreads();
        if (tid < 128) {
            int txx = tid >> 3, j = tid & 7;
            int c = (j < 4) ? (txx * 4 + j) : (txx * 4 + 60 + j);
            float s = 0.f, q = 0.f;
#pragma unroll
            for (int t = 0; t < 16; ++t) {
                s += rs[(t * 16 + txx) * 8 + j];
                q += rq[(t * 16 + txx) * 8 + j];
            }
            atomicAdd(&bnsum[c], s);
            atomicAdd(&bnsumsq[c], q);
        }
    }
}

// ---------------- finalize BN: scale/shift per channel ----------------
__global__ void k_bnfin(const float* __restrict__ bnsum, const float* __restrict__ bnsumsq,
                        const float* __restrict__ gamma, const float* __restrict__ beta,
                        float* __restrict__ scale, float* __restrict__ shift) {
    int c = threadIdx.x;
    if (c < 128) {
        float mu = bnsum[c] * (1.0f / NN);
        float var = bnsumsq[c] * (1.0f / NN) - mu * mu;
        float rs = rsqrtf(var + BN_EPS);
        float g = rs * gamma[c];
        scale[c] = g;
        shift[c] = beta[c] - mu * g;
    }
}

extern "C" void kernel_launch(void* const* d_in, const int* in_sizes, int n_in,
                              void* d_out, int out_size, void* d_ws, size_t ws_size,
                              hipStream_t stream) {
    const float* x     = (const float*)d_in[0];
    const int*   ei    = (const int*)d_in[1];
    const float* W1    = (const float*)d_in[2];
    const float* b1    = (const float*)d_in[3];
    const float* gamma = (const float*)d_in[4];
    const float* beta  = (const float*)d_in[5];
    const float* W2    = (const float*)d_in[6];
    const float* b2    = (const float*)d_in[7];
    const float* eps   = (const float*)d_in[8];

    char* ws = (char*)d_ws;
    // ws layout (all offsets 256B-aligned): cursor[40000] | srclist[40000*64] | hbuf[40000*128] | bn[512]
    int*   cursor  = (int*)(ws + 0);
    int*   srclist = (int*)(ws + 160000);
    float* hbuf    = (float*)(ws + 10400000);
    float* bn      = (float*)(ws + 30880000);
    float* bnsum   = bn;
    float* bnsumsq = bn + 128;
    float* scale   = bn + 256;
    float* shift   = bn + 384;
    float* h1      = (float*)d_out;   // reuse d_out as h1 scratch (in-place-safe GEMM2)

    k_zero<<<158, 256, 0, stream>>>(cursor, bn);
    k_bucket<<<2500, 256, 0, stream>>>(ei, cursor, srclist);
    k_gather<<<10000, 256, 0, stream>>>(x, cursor, srclist, eps, hbuf);
    k_gemm<true, false><<<625, 256, 0, stream>>>(hbuf, W1, b1, h1, nullptr, nullptr, bnsum, bnsumsq);
    k_bnfin<<<1, 128, 0, stream>>>(bnsum, bnsumsq, gamma, beta, scale, shift);
    k_gemm<false, true><<<625, 256, 0, stream>>>(h1, W2, b2, (float*)d_out, scale, shift, nullptr, nullptr);
}

// Round 2
// 154.148 us; speedup vs baseline: 1.1469x; 1.1469x over previous
//
#include <hip/hip_runtime.h>

#define NN 40000
#define NE 640000
#define CAP 64
#define BN_EPS 1e-5f

// ---------------- zero cursor + BN accumulators ----------------
__global__ __launch_bounds__(256) void k_zero(int* __restrict__ cursor, float* __restrict__ bn) {
    int i = blockIdx.x * 256 + threadIdx.x;
    if (i < NN) cursor[i] = 0;
    int j = i - NN;
    if (j >= 0 && j < 256) bn[j] = 0.f;
}

// ---------------- bucket edges by dst (1 int atomic per edge) ----------------
__global__ __launch_bounds__(256) void k_bucket(const int* __restrict__ ei, int* __restrict__ cursor,
                                                int* __restrict__ srclist) {
    int e = blockIdx.x * 256 + threadIdx.x;
    if (e >= NE) return;
    int s = ei[e];
    int d = ei[NE + e];
    int pos = atomicAdd(&cursor[d], 1);
    if (pos < CAP) srclist[d * CAP + pos] = s;
}

// ---------------- wave-per-node gather-sum: hbuf = (1+eps)*x + sum_neighbors x ----------------
// The whole 64-entry src list is loaded in ONE coalesced 256B read (one int per lane),
// then broadcast via readlane (SALU, no memory op). Row loads are unrolled x8 so 8
// independent 512B reads are in flight per wave -> latency-hiding instead of a serial
// lst[i] -> x[s] dependency chain.
__global__ __launch_bounds__(256) void k_gather(const float* __restrict__ x, const int* __restrict__ cursor,
                                                const int* __restrict__ srclist, const float* __restrict__ epsp,
                                                float* __restrict__ hbuf) {
    int wid = blockIdx.x * 4 + (threadIdx.x >> 6);   // one wave per dst node; grid*4 == NN exactly
    int lane = threadIdx.x & 63;
    const float2* xv = (const float2*)x;
    int deg = cursor[wid];
    deg = deg > CAP ? CAP : deg;
    int sv = srclist[wid * CAP + lane];              // full neighbor list in wave registers
    float2 self = xv[wid * 64 + lane];
    float e1 = 1.f + epsp[0];
    float a0 = self.x * e1, a1 = self.y * e1;
    int i = 0;
    for (; i + 8 <= deg; i += 8) {
        int s0 = __builtin_amdgcn_readlane(sv, i);
        int s1 = __builtin_amdgcn_readlane(sv, i + 1);
        int s2 = __builtin_amdgcn_readlane(sv, i + 2);
        int s3 = __builtin_amdgcn_readlane(sv, i + 3);
        int s4 = __builtin_amdgcn_readlane(sv, i + 4);
        int s5 = __builtin_amdgcn_readlane(sv, i + 5);
        int s6 = __builtin_amdgcn_readlane(sv, i + 6);
        int s7 = __builtin_amdgcn_readlane(sv, i + 7);
        float2 v0 = xv[(size_t)s0 * 64 + lane];
        float2 v1 = xv[(size_t)s1 * 64 + lane];
        float2 v2 = xv[(size_t)s2 * 64 + lane];
        float2 v3 = xv[(size_t)s3 * 64 + lane];
        float2 v4 = xv[(size_t)s4 * 64 + lane];
        float2 v5 = xv[(size_t)s5 * 64 + lane];
        float2 v6 = xv[(size_t)s6 * 64 + lane];
        float2 v7 = xv[(size_t)s7 * 64 + lane];
        a0 += v0.x + v1.x + v2.x + v3.x + v4.x + v5.x + v6.x + v7.x;
        a1 += v0.y + v1.y + v2.y + v3.y + v4.y + v5.y + v6.y + v7.y;
    }
    for (; i < deg; ++i) {
        int s = __builtin_amdgcn_readlane(sv, i);
        float2 v = xv[(size_t)s * 64 + lane];
        a0 += v.x; a1 += v.y;
    }
    ((float2*)hbuf)[wid * 64 + lane] = make_float2(a0, a1);
}

// ---------------- fp32 vector GEMM: out[M,128] = A[M,128] @ W[128,128]^T + bias ----------------
// STATS: accumulate per-channel sum/sumsq of output (for BN).  BN: apply y=relu(a*scale+shift) to A on load.
template<bool STATS, bool BN>
__global__ __launch_bounds__(256) void k_gemm(const float* __restrict__ A, const float* __restrict__ W,
                                              const float* __restrict__ bias, float* __restrict__ out,
                                              const float* __restrict__ scale, const float* __restrict__ shift,
                                              float* __restrict__ bnsum, float* __restrict__ bnsumsq) {
    __shared__ float sA[64 * 65];    // 64 rows x 64 k (stride 65: <=2-way bank aliasing, free)
    __shared__ float sW[128 * 65];   // 128 cols x 64 k
    const int tid = threadIdx.x;
    const int tx = tid & 15;
    const int ty = tid >> 4;
    const int rb = blockIdx.x * 64;  // 40000 % 64 == 0: no row guards needed

    float acc[4][8];
#pragma unroll
    for (int i = 0; i < 4; ++i)
#pragma unroll
        for (int j = 0; j < 8; ++j) acc[i][j] = 0.f;

    for (int kb = 0; kb < 128; kb += 64) {
        __syncthreads();
        // stage A-tile (64x64), optionally with BN+ReLU fused
#pragma unroll
        for (int it = 0; it < 4; ++it) {
            int idx = it * 256 + tid;
            int r = idx >> 4;
            int kq = idx & 15;
            float4 v = *(const float4*)&A[(size_t)(rb + r) * 128 + kb + kq * 4];
            if (BN) {
                float4 sc = *(const float4*)&scale[kb + kq * 4];
                float4 sh = *(const float4*)&shift[kb + kq * 4];
                v.x = fmaxf(0.f, fmaf(v.x, sc.x, sh.x));
                v.y = fmaxf(0.f, fmaf(v.y, sc.y, sh.y));
                v.z = fmaxf(0.f, fmaf(v.z, sc.z, sh.z));
                v.w = fmaxf(0.f, fmaf(v.w, sc.w, sh.w));
            }
            float* d = &sA[r * 65 + kq * 4];
            d[0] = v.x; d[1] = v.y; d[2] = v.z; d[3] = v.w;
        }
        // stage W-tile (128x64), row-major as given (out[c] = sum_k A[k]*W[c][k])
#pragma unroll
        for (int it = 0; it < 8; ++it) {
            int idx = it * 256 + tid;
            int c = idx >> 4;
            int kq = idx & 15;
            float4 v = *(const float4*)&W[c * 128 + kb + kq * 4];
            float* d = &sW[c * 65 + kq * 4];
            d[0] = v.x; d[1] = v.y; d[2] = v.z; d[3] = v.w;
        }
        __syncthreads();
#pragma unroll 4
        for (int k = 0; k < 64; ++k) {
            float a[4], w[8];
#pragma unroll
            for (int i = 0; i < 4; ++i) a[i] = sA[(ty * 4 + i) * 65 + k];
#pragma unroll
            for (int j = 0; j < 4; ++j) {
                w[j]     = sW[(tx * 4 + j) * 65 + k];
                w[j + 4] = sW[(tx * 4 + 64 + j) * 65 + k];
            }
#pragma unroll
            for (int i = 0; i < 4; ++i)
#pragma unroll
                for (int j = 0; j < 8; ++j)
                    acc[i][j] = fmaf(a[i], w[j], acc[i][j]);
        }
    }

    const int c0 = tx * 4, c1 = tx * 4 + 64;
    float4 b0 = *(const float4*)&bias[c0];
    float4 b1v = *(const float4*)&bias[c1];
    float cs[8], cq[8];
#pragma unroll
    for (int j = 0; j < 8; ++j) { cs[j] = 0.f; cq[j] = 0.f; }
#pragma unroll
    for (int i = 0; i < 4; ++i) {
        int row = rb + ty * 4 + i;
        float4 v0, v1;
        v0.x = acc[i][0] + b0.x;  v0.y = acc[i][1] + b0.y;  v0.z = acc[i][2] + b0.z;  v0.w = acc[i][3] + b0.w;
        v1.x = acc[i][4] + b1v.x; v1.y = acc[i][5] + b1v.y; v1.z = acc[i][6] + b1v.z; v1.w = acc[i][7] + b1v.w;
        *(float4*)&out[(size_t)row * 128 + c0] = v0;
        *(float4*)&out[(size_t)row * 128 + c1] = v1;
        if (STATS) {
            cs[0] += v0.x; cq[0] += v0.x * v0.x;
            cs[1] += v0.y; cq[1] += v0.y * v0.y;
            cs[2] += v0.z; cq[2] += v0.z * v0.z;
            cs[3] += v0.w; cq[3] += v0.w * v0.w;
            cs[4] += v1.x; cq[4] += v1.x * v1.x;
            cs[5] += v1.y; cq[5] += v1.y * v1.y;
            cs[6] += v1.z; cq[6] += v1.z * v1.z;
            cs[7] += v1.w; cq[7] += v1.w * v1.w;
        }
    }
    if (STATS) {
        __syncthreads();           // everyone done reading sA/sW
        float* rs = sA;            // reuse LDS: 256 threads x 8 floats
        float* rq = sW;
#pragma unroll
        for (int j = 0; j < 8; ++j) { rs[tid * 8 + j] = cs[j]; rq[tid * 8 + j] = cq[j]; }
        __syncthreads();
        if (tid < 128) {
            int txx = tid >> 3, j = tid & 7;
            int c = (j < 4) ? (txx * 4 + j) : (txx * 4 + 60 + j);
            float s = 0.f, q = 0.f;
#pragma unroll
            for (int t = 0; t < 16; ++t) {
                s += rs[(t * 16 + txx) * 8 + j];
                q += rq[(t * 16 + txx) * 8 + j];
            }
            atomicAdd(&bnsum[c], s);
            atomicAdd(&bnsumsq[c], q);
        }
    }
}

// ---------------- finalize BN: scale/shift per channel ----------------
__global__ void k_bnfin(const float* __restrict__ bnsum, const float* __restrict__ bnsumsq,
                        const float* __restrict__ gamma, const float* __restrict__ beta,
                        float* __restrict__ scale, float* __restrict__ shift) {
    int c = threadIdx.x;
    if (c < 128) {
        float mu = bnsum[c] * (1.0f / NN);
        float var = bnsumsq[c] * (1.0f / NN) - mu * mu;
        float rs = rsqrtf(var + BN_EPS);
        float g = rs * gamma[c];
        scale[c] = g;
        shift[c] = beta[c] - mu * g;
    }
}

extern "C" void kernel_launch(void* const* d_in, const int* in_sizes, int n_in,
                              void* d_out, int out_size, void* d_ws, size_t ws_size,
                              hipStream_t stream) {
    const float* x     = (const float*)d_in[0];
    const int*   ei    = (const int*)d_in[1];
    const float* W1    = (const float*)d_in[2];
    const float* b1    = (const float*)d_in[3];
    const float* gamma = (const float*)d_in[4];
    const float* beta  = (const float*)d_in[5];
    const float* W2    = (const float*)d_in[6];
    const float* b2    = (const float*)d_in[7];
    const float* eps   = (const float*)d_in[8];

    char* ws = (char*)d_ws;
    // ws layout (all offsets 256B-aligned): cursor[40000] | srclist[40000*64] | hbuf[40000*128] | bn[512]
    int*   cursor  = (int*)(ws + 0);
    int*   srclist = (int*)(ws + 160000);
    float* hbuf    = (float*)(ws + 10400000);
    float* bn      = (float*)(ws + 30880000);
    float* bnsum   = bn;
    float* bnsumsq = bn + 128;
    float* scale   = bn + 256;
    float* shift   = bn + 384;
    float* h1      = (float*)d_out;   // reuse d_out as h1 scratch (in-place-safe GEMM2)

    k_zero<<<158, 256, 0, stream>>>(cursor, bn);
    k_bucket<<<2500, 256, 0, stream>>>(ei, cursor, srclist);
    k_gather<<<10000, 256, 0, stream>>>(x, cursor, srclist, eps, hbuf);
    k_gemm<true, false><<<625, 256, 0, stream>>>(hbuf, W1, b1, h1, nullptr, nullptr, bnsum, bnsumsq);
    k_bnfin<<<1, 128, 0, stream>>>(bnsum, bnsumsq, gamma, beta, scale, shift);
    k_gemm<false, true><<<625, 256, 0, stream>>>(h1, W2, b2, (float*)d_out, scale, shift, nullptr, nullptr);
}